// Round 5
// baseline (748.240 us; speedup 1.0000x reference)
//
#include <hip/hip_runtime.h>

// Splat conv (full true convolution):
//   out[oi, oj] = sum_{di,dj in [0,5)} in[oi-di, oj-dj] * f[di][dj]
// in:  8192 x 8192 fp32, out: 8196 x 8196 fp32 (no bias in forward).
//
// v5: v4's streaming column-strip schedule, spill-proofed.
// v4 post-mortem: W[8][2]/P[4][2] arrays + rotate loop were demoted to
// scratch (WRITE_SIZE 624 MB vs 268 MB output, VGPR=64) -> 288 us.
// v5 keeps the 8-row rolling window in 16 NAMED float4 variables; the
// window "rotation" is done by duplicating the loop body with rotated
// names (zero copies, every access a named scalar -> guaranteed SROA).
// Per body: contributions of old rows 0..3, then prefetch-overwrite those
// 4 slots with the next 4 rows (consumed one full body later, ~800 FMA
// cycles of latency cover), then contributions of rows 4..7, then store.

#define IN_H 8192
#define IN_W 8192
#define OUT_H 8196
#define OUT_W 8196
#define NG 2049   // float4 groups per output row
#define NRG 2049  // output row-groups of 4 (2049*4 == 8196)
#define SPAN 16   // row-groups per fast-path strip (64 output rows)

__device__ __forceinline__ float sgpr_f32(float v) {
  return __int_as_float(__builtin_amdgcn_readfirstlane(__float_as_int(v)));
}

// Contribution of window slot RR (holding input row n-4+RR) to acc[4][4]
// (output rows n..n+3). RR is a literal -> di test folds at compile time.
#define CONTRIB(RR, SA, SB)                                               \
  do {                                                                    \
    float x[8];                                                           \
    x[0] = (SA).x; x[1] = (SA).y; x[2] = (SA).z; x[3] = (SA).w;           \
    x[4] = (SB).x; x[5] = (SB).y; x[6] = (SB).z; x[7] = (SB).w;           \
    _Pragma("unroll") for (int k = 0; k < 4; ++k) {                       \
      const int di = k + 4 - (RR);                                        \
      if (di >= 0 && di <= 4) {                                           \
        _Pragma("unroll") for (int dj = 0; dj < 5; ++dj) {                \
          const float w = f[di * 5 + dj];                                 \
          _Pragma("unroll") for (int m = 0; m < 4; ++m)                   \
              acc[k][m] += x[m + 4 - dj] * w;                             \
        }                                                                 \
      }                                                                   \
    }                                                                     \
  } while (0)

// One row-group: consume window (slots in the given name order), prefetch
// the next 4 input rows into slots 0..3 (overwritten AFTER their reads),
// store 4 output rows.
#define BODY(S0a, S0b, S1a, S1b, S2a, S2b, S3a, S3b,                      \
             S4a, S4b, S5a, S5b, S6a, S6b, S7a, S7b)                      \
  do {                                                                    \
    float acc[4][4] = {{0.f}};                                            \
    CONTRIB(0, S0a, S0b);                                                 \
    CONTRIB(1, S1a, S1b);                                                 \
    CONTRIB(2, S2a, S2b);                                                 \
    CONTRIB(3, S3a, S3b);                                                 \
    S0a = *(const float4*)(rp); S0b = *(const float4*)(rp + 4); rp += IN_W; \
    S1a = *(const float4*)(rp); S1b = *(const float4*)(rp + 4); rp += IN_W; \
    S2a = *(const float4*)(rp); S2b = *(const float4*)(rp + 4); rp += IN_W; \
    S3a = *(const float4*)(rp); S3b = *(const float4*)(rp + 4); rp += IN_W; \
    CONTRIB(4, S4a, S4b);                                                 \
    CONTRIB(5, S5a, S5b);                                                 \
    CONTRIB(6, S6a, S6b);                                                 \
    CONTRIB(7, S7a, S7b);                                                 \
    *(float4*)(op) = make_float4(acc[0][0], acc[0][1], acc[0][2], acc[0][3]); \
    *(float4*)(op + OUT_W) = make_float4(acc[1][0], acc[1][1], acc[1][2], acc[1][3]); \
    *(float4*)(op + 2 * OUT_W) = make_float4(acc[2][0], acc[2][1], acc[2][2], acc[2][3]); \
    *(float4*)(op + 3 * OUT_W) = make_float4(acc[3][0], acc[3][1], acc[3][2], acc[3][3]); \
    op += 4 * OUT_W;                                                      \
  } while (0)

// Final row-group of a strip: consume only, no prefetch.
#define FINAL(S0a, S0b, S1a, S1b, S2a, S2b, S3a, S3b,                     \
              S4a, S4b, S5a, S5b, S6a, S6b, S7a, S7b)                     \
  do {                                                                    \
    float acc[4][4] = {{0.f}};                                            \
    CONTRIB(0, S0a, S0b);                                                 \
    CONTRIB(1, S1a, S1b);                                                 \
    CONTRIB(2, S2a, S2b);                                                 \
    CONTRIB(3, S3a, S3b);                                                 \
    CONTRIB(4, S4a, S4b);                                                 \
    CONTRIB(5, S5a, S5b);                                                 \
    CONTRIB(6, S6a, S6b);                                                 \
    CONTRIB(7, S7a, S7b);                                                 \
    *(float4*)(op) = make_float4(acc[0][0], acc[0][1], acc[0][2], acc[0][3]); \
    *(float4*)(op + OUT_W) = make_float4(acc[1][0], acc[1][1], acc[1][2], acc[1][3]); \
    *(float4*)(op + 2 * OUT_W) = make_float4(acc[2][0], acc[2][1], acc[2][2], acc[2][3]); \
    *(float4*)(op + 3 * OUT_W) = make_float4(acc[3][0], acc[3][1], acc[3][2], acc[3][3]); \
  } while (0)

__global__ __launch_bounds__(256, 4) void splat_conv_kernel(
    const float* __restrict__ in, const float* __restrict__ flt,
    float* __restrict__ out) {
  const int g = blockIdx.x * 64 + threadIdx.x;  // col group (float4)
  if (g >= NG) return;
  const int strip = blockIdx.y * 4 + threadIdx.y;
  const int rg0 = strip * SPAN;
  if (rg0 >= NRG) return;
  const int rg1 = (rg0 + SPAN < NRG) ? rg0 + SPAN : NRG;

  // Filter into SGPRs (uniform across the wave).
  float f[25];
#pragma unroll
  for (int i = 0; i < 25; ++i) f[i] = sgpr_f32(flt[i]);

  const int c0 = 4 * g - 4;  // base input col (16B aligned)
  const bool col_int = (g >= 1) & (g <= NG - 2);
  // Fast path needs rows 4*rg0-4 .. 4*rg0+63 inside [0, IN_H) and a full
  // SPAN strip: rg0 in [16, 2032], all multiples of 16 -> rg1 = rg0+16.
  const bool rows_ok = (rg0 >= 1) & (rg1 == rg0 + SPAN) & (rg1 - 1 <= 2047);

  if (col_int & rows_ok) {
    // ---------- FAST streaming path (niter == 16, compile-time) ----------
    const float* rp = in + (size_t)(4 * rg0 - 4) * IN_W + c0;
    float* op = out + (size_t)(4 * rg0) * OUT_W + 4 * g;

    float4 W0a, W0b, W1a, W1b, W2a, W2b, W3a, W3b;
    float4 W4a, W4b, W5a, W5b, W6a, W6b, W7a, W7b;
    // Prime: rows 4*rg0-4 .. 4*rg0+3 into slots 0..7.
    W0a = *(const float4*)(rp); W0b = *(const float4*)(rp + 4); rp += IN_W;
    W1a = *(const float4*)(rp); W1b = *(const float4*)(rp + 4); rp += IN_W;
    W2a = *(const float4*)(rp); W2b = *(const float4*)(rp + 4); rp += IN_W;
    W3a = *(const float4*)(rp); W3b = *(const float4*)(rp + 4); rp += IN_W;
    W4a = *(const float4*)(rp); W4b = *(const float4*)(rp + 4); rp += IN_W;
    W5a = *(const float4*)(rp); W5b = *(const float4*)(rp + 4); rp += IN_W;
    W6a = *(const float4*)(rp); W6b = *(const float4*)(rp + 4); rp += IN_W;
    W7a = *(const float4*)(rp); W7b = *(const float4*)(rp + 4); rp += IN_W;

    // 16 row-groups: 7 rotated pairs + 1 prefetching body + final.
#pragma unroll 1
    for (int p = 0; p < 7; ++p) {
      BODY(W0a, W0b, W1a, W1b, W2a, W2b, W3a, W3b,
           W4a, W4b, W5a, W5b, W6a, W6b, W7a, W7b);
      BODY(W4a, W4b, W5a, W5b, W6a, W6b, W7a, W7b,
           W0a, W0b, W1a, W1b, W2a, W2b, W3a, W3b);
    }
    BODY(W0a, W0b, W1a, W1b, W2a, W2b, W3a, W3b,
         W4a, W4b, W5a, W5b, W6a, W6b, W7a, W7b);
    FINAL(W4a, W4b, W5a, W5b, W6a, W6b, W7a, W7b,
          W0a, W0b, W1a, W1b, W2a, W2b, W3a, W3b);
  } else {
    // ---------- SLOW guarded path (image edges; ~2% of work) ----------
    const bool lo_ok = (g != 0);
    const bool hi_ok = (g != NG - 1);
    for (int rg = rg0; rg < rg1; ++rg) {
      const int orow = rg * 4;
      float4 A[8], B[8];
#pragma unroll
      for (int rr = 0; rr < 8; ++rr) {
        const int r = orow - 4 + rr;
        A[rr] = make_float4(0.f, 0.f, 0.f, 0.f);
        B[rr] = make_float4(0.f, 0.f, 0.f, 0.f);
        if (r >= 0 && r < IN_H) {
          const float* rp = in + (size_t)r * IN_W + c0;
          if (lo_ok) A[rr] = *(const float4*)(rp);
          if (hi_ok) B[rr] = *(const float4*)(rp + 4);
        }
      }
      float acc[4][4];
#pragma unroll
      for (int k = 0; k < 4; ++k)
#pragma unroll
        for (int m = 0; m < 4; ++m) acc[k][m] = 0.f;
#pragma unroll
      for (int rr = 0; rr < 8; ++rr) {
        float x[8];
        x[0] = A[rr].x; x[1] = A[rr].y; x[2] = A[rr].z; x[3] = A[rr].w;
        x[4] = B[rr].x; x[5] = B[rr].y; x[6] = B[rr].z; x[7] = B[rr].w;
#pragma unroll
        for (int k = 0; k < 4; ++k) {
          const int di = k + 4 - rr;
          if (di < 0 || di > 4) continue;
#pragma unroll
          for (int dj = 0; dj < 5; ++dj) {
            const float w = f[di * 5 + dj];
#pragma unroll
            for (int m = 0; m < 4; ++m) acc[k][m] += x[m + 4 - dj] * w;
          }
        }
      }
      float* o = out + (size_t)orow * OUT_W + 4 * g;
#pragma unroll
      for (int k = 0; k < 4; ++k) {
        *(float4*)(o) = make_float4(acc[k][0], acc[k][1], acc[k][2], acc[k][3]);
        o += OUT_W;
      }
    }
  }
}

extern "C" void kernel_launch(void* const* d_in, const int* in_sizes, int n_in,
                              void* d_out, int out_size, void* d_ws,
                              size_t ws_size, hipStream_t stream) {
  const float* in = (const float*)d_in[0];
  const float* flt = (const float*)d_in[1];
  // d_in[2] = bias: NOT used by the forward reference.
  float* out = (float*)d_out;

  const int nstrips = (NRG + SPAN - 1) / SPAN;   // 129
  dim3 block(64, 4);                             // 256 threads
  dim3 grid((NG + 63) / 64, (nstrips + 3) / 4);  // 33 x 33
  splat_conv_kernel<<<grid, block, 0, stream>>>(in, flt, out);
}

// Round 6
// 684.839 us; speedup vs baseline: 1.0926x; 1.0926x over previous
//
#include <hip/hip_runtime.h>

// Splat conv (full true convolution):
//   out[oi, oj] = sum_{di,dj in [0,5)} in[oi-di, oj-dj] * f[di][dj]
// in:  8192 x 8192 fp32, out: 8196 x 8196 fp32 (no bias in forward).
//
// v6: v5's named-register rolling-window streaming, with the REAL spill fix.
// v4/v5 post-mortem: backend targeted 8 waves/EU (64-VGPR budget;
// launch_bounds' 2nd arg is only a MINIMUM) and spilled the ~100 live regs
// to scratch -> WRITE_SIZE 853 MB vs 268 MB output. amdgpu_waves_per_eu(4,4)
// pins the occupancy target to 4 waves/EU -> 128-VGPR budget, spill-free.
// SPAN 16->8: 2145 blocks (~8.4/CU) cuts the load-imbalance tail.

#define IN_H 8192
#define IN_W 8192
#define OUT_H 8196
#define OUT_W 8196
#define NG 2049   // float4 groups per output row
#define NRG 2049  // output row-groups of 4 (2049*4 == 8196)
#define SPAN 8    // row-groups per fast-path strip (32 output rows)

__device__ __forceinline__ float sgpr_f32(float v) {
  return __int_as_float(__builtin_amdgcn_readfirstlane(__float_as_int(v)));
}

// Contribution of window slot RR (holding input row n-4+RR) to acc[4][4]
// (output rows n..n+3). RR is a literal -> di test folds at compile time.
#define CONTRIB(RR, SA, SB)                                               \
  do {                                                                    \
    float x[8];                                                           \
    x[0] = (SA).x; x[1] = (SA).y; x[2] = (SA).z; x[3] = (SA).w;           \
    x[4] = (SB).x; x[5] = (SB).y; x[6] = (SB).z; x[7] = (SB).w;           \
    _Pragma("unroll") for (int k = 0; k < 4; ++k) {                       \
      const int di = k + 4 - (RR);                                        \
      if (di >= 0 && di <= 4) {                                           \
        _Pragma("unroll") for (int dj = 0; dj < 5; ++dj) {                \
          const float w = f[di * 5 + dj];                                 \
          _Pragma("unroll") for (int m = 0; m < 4; ++m)                   \
              acc[k][m] += x[m + 4 - dj] * w;                             \
        }                                                                 \
      }                                                                   \
    }                                                                     \
  } while (0)

// One row-group: consume window slots (in given name order), prefetch the
// next 4 input rows into slots 0..3 (overwritten AFTER their reads), store
// 4 output rows.
#define BODY(S0a, S0b, S1a, S1b, S2a, S2b, S3a, S3b,                      \
             S4a, S4b, S5a, S5b, S6a, S6b, S7a, S7b)                      \
  do {                                                                    \
    float acc[4][4] = {{0.f}};                                            \
    CONTRIB(0, S0a, S0b);                                                 \
    CONTRIB(1, S1a, S1b);                                                 \
    CONTRIB(2, S2a, S2b);                                                 \
    CONTRIB(3, S3a, S3b);                                                 \
    S0a = *(const float4*)(rp); S0b = *(const float4*)(rp + 4); rp += IN_W; \
    S1a = *(const float4*)(rp); S1b = *(const float4*)(rp + 4); rp += IN_W; \
    S2a = *(const float4*)(rp); S2b = *(const float4*)(rp + 4); rp += IN_W; \
    S3a = *(const float4*)(rp); S3b = *(const float4*)(rp + 4); rp += IN_W; \
    CONTRIB(4, S4a, S4b);                                                 \
    CONTRIB(5, S5a, S5b);                                                 \
    CONTRIB(6, S6a, S6b);                                                 \
    CONTRIB(7, S7a, S7b);                                                 \
    *(float4*)(op) = make_float4(acc[0][0], acc[0][1], acc[0][2], acc[0][3]); \
    *(float4*)(op + OUT_W) = make_float4(acc[1][0], acc[1][1], acc[1][2], acc[1][3]); \
    *(float4*)(op + 2 * OUT_W) = make_float4(acc[2][0], acc[2][1], acc[2][2], acc[2][3]); \
    *(float4*)(op + 3 * OUT_W) = make_float4(acc[3][0], acc[3][1], acc[3][2], acc[3][3]); \
    op += 4 * OUT_W;                                                      \
  } while (0)

// Final row-group of a strip: consume only, no prefetch.
#define FINAL(S0a, S0b, S1a, S1b, S2a, S2b, S3a, S3b,                     \
              S4a, S4b, S5a, S5b, S6a, S6b, S7a, S7b)                     \
  do {                                                                    \
    float acc[4][4] = {{0.f}};                                            \
    CONTRIB(0, S0a, S0b);                                                 \
    CONTRIB(1, S1a, S1b);                                                 \
    CONTRIB(2, S2a, S2b);                                                 \
    CONTRIB(3, S3a, S3b);                                                 \
    CONTRIB(4, S4a, S4b);                                                 \
    CONTRIB(5, S5a, S5b);                                                 \
    CONTRIB(6, S6a, S6b);                                                 \
    CONTRIB(7, S7a, S7b);                                                 \
    *(float4*)(op) = make_float4(acc[0][0], acc[0][1], acc[0][2], acc[0][3]); \
    *(float4*)(op + OUT_W) = make_float4(acc[1][0], acc[1][1], acc[1][2], acc[1][3]); \
    *(float4*)(op + 2 * OUT_W) = make_float4(acc[2][0], acc[2][1], acc[2][2], acc[2][3]); \
    *(float4*)(op + 3 * OUT_W) = make_float4(acc[3][0], acc[3][1], acc[3][2], acc[3][3]); \
  } while (0)

__global__ __launch_bounds__(256)
__attribute__((amdgpu_waves_per_eu(4, 4)))
void splat_conv_kernel(
    const float* __restrict__ in, const float* __restrict__ flt,
    float* __restrict__ out) {
  const int g = blockIdx.x * 64 + threadIdx.x;  // col group (float4)
  if (g >= NG) return;
  const int strip = blockIdx.y * 4 + threadIdx.y;
  const int rg0 = strip * SPAN;
  if (rg0 >= NRG) return;
  const int rg1 = (rg0 + SPAN < NRG) ? rg0 + SPAN : NRG;

  // Filter into SGPRs (uniform across the wave).
  float f[25];
#pragma unroll
  for (int i = 0; i < 25; ++i) f[i] = sgpr_f32(flt[i]);

  const int c0 = 4 * g - 4;  // base input col (16B aligned)
  const bool col_int = (g >= 1) & (g <= NG - 2);
  // Fast path: full strip, all touched input rows in [0, IN_H).
  const bool rows_ok = (rg0 >= 1) & (rg1 == rg0 + SPAN) & (rg1 - 1 <= 2047);

  if (col_int & rows_ok) {
    // ---------- FAST streaming path (SPAN row-groups, compile-time) ------
    const float* rp = in + (size_t)(4 * rg0 - 4) * IN_W + c0;
    float* op = out + (size_t)(4 * rg0) * OUT_W + 4 * g;

    float4 W0a, W0b, W1a, W1b, W2a, W2b, W3a, W3b;
    float4 W4a, W4b, W5a, W5b, W6a, W6b, W7a, W7b;
    // Prime: rows 4*rg0-4 .. 4*rg0+3 into slots 0..7.
    W0a = *(const float4*)(rp); W0b = *(const float4*)(rp + 4); rp += IN_W;
    W1a = *(const float4*)(rp); W1b = *(const float4*)(rp + 4); rp += IN_W;
    W2a = *(const float4*)(rp); W2b = *(const float4*)(rp + 4); rp += IN_W;
    W3a = *(const float4*)(rp); W3b = *(const float4*)(rp + 4); rp += IN_W;
    W4a = *(const float4*)(rp); W4b = *(const float4*)(rp + 4); rp += IN_W;
    W5a = *(const float4*)(rp); W5b = *(const float4*)(rp + 4); rp += IN_W;
    W6a = *(const float4*)(rp); W6b = *(const float4*)(rp + 4); rp += IN_W;
    W7a = *(const float4*)(rp); W7b = *(const float4*)(rp + 4); rp += IN_W;

    // SPAN=8 row-groups: 3 rotated pairs + 1 prefetching body + final.
#pragma unroll 1
    for (int p = 0; p < SPAN / 2 - 1; ++p) {
      BODY(W0a, W0b, W1a, W1b, W2a, W2b, W3a, W3b,
           W4a, W4b, W5a, W5b, W6a, W6b, W7a, W7b);
      BODY(W4a, W4b, W5a, W5b, W6a, W6b, W7a, W7b,
           W0a, W0b, W1a, W1b, W2a, W2b, W3a, W3b);
    }
    BODY(W0a, W0b, W1a, W1b, W2a, W2b, W3a, W3b,
         W4a, W4b, W5a, W5b, W6a, W6b, W7a, W7b);
    FINAL(W4a, W4b, W5a, W5b, W6a, W6b, W7a, W7b,
          W0a, W0b, W1a, W1b, W2a, W2b, W3a, W3b);
  } else {
    // ---------- SLOW guarded path (image edges; ~2% of work) ----------
    const bool lo_ok = (g != 0);
    const bool hi_ok = (g != NG - 1);
    for (int rg = rg0; rg < rg1; ++rg) {
      const int orow = rg * 4;
      float4 A[8], B[8];
#pragma unroll
      for (int rr = 0; rr < 8; ++rr) {
        const int r = orow - 4 + rr;
        A[rr] = make_float4(0.f, 0.f, 0.f, 0.f);
        B[rr] = make_float4(0.f, 0.f, 0.f, 0.f);
        if (r >= 0 && r < IN_H) {
          const float* rp = in + (size_t)r * IN_W + c0;
          if (lo_ok) A[rr] = *(const float4*)(rp);
          if (hi_ok) B[rr] = *(const float4*)(rp + 4);
        }
      }
      float acc[4][4];
#pragma unroll
      for (int k = 0; k < 4; ++k)
#pragma unroll
        for (int m = 0; m < 4; ++m) acc[k][m] = 0.f;
#pragma unroll
      for (int rr = 0; rr < 8; ++rr) {
        float x[8];
        x[0] = A[rr].x; x[1] = A[rr].y; x[2] = A[rr].z; x[3] = A[rr].w;
        x[4] = B[rr].x; x[5] = B[rr].y; x[6] = B[rr].z; x[7] = B[rr].w;
#pragma unroll
        for (int k = 0; k < 4; ++k) {
          const int di = k + 4 - rr;
          if (di < 0 || di > 4) continue;
#pragma unroll
          for (int dj = 0; dj < 5; ++dj) {
            const float w = f[di * 5 + dj];
#pragma unroll
            for (int m = 0; m < 4; ++m) acc[k][m] += x[m + 4 - dj] * w;
          }
        }
      }
      float* o = out + (size_t)orow * OUT_W + 4 * g;
#pragma unroll
      for (int k = 0; k < 4; ++k) {
        *(float4*)(o) = make_float4(acc[k][0], acc[k][1], acc[k][2], acc[k][3]);
        o += OUT_W;
      }
    }
  }
}

extern "C" void kernel_launch(void* const* d_in, const int* in_sizes, int n_in,
                              void* d_out, int out_size, void* d_ws,
                              size_t ws_size, hipStream_t stream) {
  const float* in = (const float*)d_in[0];
  const float* flt = (const float*)d_in[1];
  // d_in[2] = bias: NOT used by the forward reference.
  float* out = (float*)d_out;

  const int nstrips = (NRG + SPAN - 1) / SPAN;   // 257
  dim3 block(64, 4);                             // 256 threads
  dim3 grid((NG + 63) / 64, (nstrips + 3) / 4);  // 33 x 65
  splat_conv_kernel<<<grid, block, 0, stream>>>(in, flt, out);
}

// Round 7
// 472.549 us; speedup vs baseline: 1.5834x; 1.4492x over previous
//
#include <hip/hip_runtime.h>

// Splat conv (full true convolution):
//   out[oi, oj] = sum_{di,dj in [0,5)} in[oi-di, oj-dj] * f[di][dj]
// in:  8192 x 8192 fp32, out: 8196 x 8196 fp32 (no bias in forward).
//
// v7: LDS-staged tile. v4/v5/v6 all tried a register-resident rolling
// window and the RA vetoed it every time (VGPR pinned at 64, ~400 MB
// scratch spill -> WRITE_SIZE 798-853 MB). This version needs only ~48
// VGPRs: the block stages a 20-row x 65-float4 input slab into LDS once
// (each input float4 loaded ONCE per block, 5 independent loads/thread),
// then all 256 threads compute a 256-col x 16-row output tile from LDS.
// All image-boundary handling is zero-fill in the stage phase; the
// compute phase is uniform and unguarded.

#define IN_H 8192
#define IN_W 8192
#define IN_WG 2048   // input float4 groups per row
#define OUT_H 8196
#define OUT_W 8196
#define NG 2049      // output float4 groups per row
#define TROWS 16     // output rows per block
#define LDS_R 20     // staged input rows (TROWS + 4 halo)
#define LDS_C 66     // staged float4 cols (65 used + 1 pad)

__device__ __forceinline__ float sgpr_f32(float v) {
  return __int_as_float(__builtin_amdgcn_readfirstlane(__float_as_int(v)));
}

__global__ __launch_bounds__(256) void splat_conv_kernel(
    const float* __restrict__ in, const float* __restrict__ flt,
    float* __restrict__ out) {
  __shared__ float4 tile[LDS_R][LDS_C];

  const int tx = threadIdx.x;             // 0..63 : col group within tile
  const int ty = threadIdx.y;             // 0..3  : row quad within tile
  const int G0 = blockIdx.x * 64;         // first output f4 group of block
  const int orow0 = blockIdx.y * TROWS;   // first output row of block

  // Filter into SGPRs (uniform across the wave).
  float f[25];
#pragma unroll
  for (int i = 0; i < 25; ++i) f[i] = sgpr_f32(flt[i]);

  // ---- Stage: LDS col c holds input f4 group (G0-1+c); row r holds
  // input row (orow0-4+r). OOB -> zeros (this IS the boundary handling).
  {
    const int igb = G0 - 1;
#pragma unroll
    for (int r = ty; r < LDS_R; r += 4) {  // wave ty does rows ty,ty+4,...
      const int ir = orow0 - 4 + r;
      const bool rok = (ir >= 0) & (ir < IN_H);
      {
        const int ig = igb + tx;
        float4 v = make_float4(0.f, 0.f, 0.f, 0.f);
        if (rok & (ig >= 0) & (ig < IN_WG))
          v = *(const float4*)(in + (size_t)ir * IN_W + 4 * ig);
        tile[r][tx] = v;
      }
      if (tx == 0) {  // 65th staged column
        const int ig = igb + 64;
        float4 v = make_float4(0.f, 0.f, 0.f, 0.f);
        if (rok & (ig < IN_WG))
          v = *(const float4*)(in + (size_t)ir * IN_W + 4 * ig);
        tile[r][64] = v;
      }
    }
  }
  __syncthreads();

  // ---- Compute: output rows orow0+4*ty .. +3, output f4 group G0+tx.
  // Input row (orow-di) lives at LDS row 4*ty + (k+4-di); input f4
  // groups g-1, g live at LDS cols tx, tx+1.
  float acc[4][4] = {{0.f, 0.f, 0.f, 0.f}};
  const int rbase = 4 * ty;
#pragma unroll
  for (int rr = 0; rr < 8; ++rr) {
    const float4 a = tile[rbase + rr][tx];
    const float4 b = tile[rbase + rr][tx + 1];
    float x[8];
    x[0] = a.x; x[1] = a.y; x[2] = a.z; x[3] = a.w;
    x[4] = b.x; x[5] = b.y; x[6] = b.z; x[7] = b.w;
#pragma unroll
    for (int k = 0; k < 4; ++k) {
      const int di = k + 4 - rr;
      if (di >= 0 && di <= 4) {
#pragma unroll
        for (int dj = 0; dj < 5; ++dj) {
          const float w = f[di * 5 + dj];
#pragma unroll
          for (int m = 0; m < 4; ++m) acc[k][m] += x[m + 4 - dj] * w;
        }
      }
    }
  }

  // ---- Store: 4 coalesced float4 rows, guarded at right/bottom edges.
  const int g = G0 + tx;
  if (g < NG) {
    float* op = out + (size_t)(orow0 + 4 * ty) * OUT_W + 4 * g;
#pragma unroll
    for (int k = 0; k < 4; ++k) {
      const int orow = orow0 + 4 * ty + k;
      if (orow < OUT_H)
        *(float4*)(op) = make_float4(acc[k][0], acc[k][1], acc[k][2], acc[k][3]);
      op += OUT_W;
    }
  }
}

extern "C" void kernel_launch(void* const* d_in, const int* in_sizes, int n_in,
                              void* d_out, int out_size, void* d_ws,
                              size_t ws_size, hipStream_t stream) {
  const float* in = (const float*)d_in[0];
  const float* flt = (const float*)d_in[1];
  // d_in[2] = bias: NOT used by the forward reference.
  float* out = (float*)d_out;

  dim3 block(64, 4);  // 256 threads; one wave per ty row-quad
  dim3 grid((NG + 63) / 64, (OUT_H + TROWS - 1) / TROWS);  // 33 x 513
  splat_conv_kernel<<<grid, block, 0, stream>>>(in, flt, out);
}